// Round 18
// baseline (213.529 us; speedup 1.0000x reference)
//
#include <hip/hip_runtime.h>
#include <math.h>

// GCN 2-layer, N nodes, E edges, 64 -> 64 -> 32 channels.
// R18 = R17 with longer sort segments: BNODES 128->256, CHUNK 8192->12288.
// Segment length E/(NC*NB) goes 10.5 -> 31 edges: 16-lane subgroup walks in
// compact2/wsumk amortize 3x better, meta shrinks 3x. dl (dst&255) still fits
// the (dl<<17)|id payload (25 bits).
//   pooled = (1/N) * Sum_s c_s * relu(out1_s + b1) @ W2 + b2
//   c_s = dinv_s * (wsum_s + dinv_s),  wsum_s = Sum_{e: src=s} dinv[dst_e]

#define C1 64
#define C2 32
#define CHUNK 12288
#define BNODES 256

typedef __attribute__((ext_vector_type(8))) short bf16x8;
typedef __attribute__((ext_vector_type(4))) float f32x4;
typedef __attribute__((ext_vector_type(2))) float f32x2;

#if __has_builtin(__builtin_amdgcn_cvt_scalef32_pk_f32_fp4) && \
    __has_builtin(__builtin_amdgcn_cvt_scalef32_pk_fp4_f32)
#define HAVE_HW_FP4 1
#else
#define HAVE_HW_FP4 0
#endif

__device__ __forceinline__ unsigned short f2bf(float f) {
    unsigned u = __float_as_uint(f);
    u = (u + 0x7FFFu + ((u >> 16) & 1u)) >> 16;
    return (unsigned short)u;
}
// ---- fp8 e4m3fn (OCP) software encode (exact bit pattern) ----
__device__ __forceinline__ unsigned f2fp8(float f) {
    unsigned s = (__float_as_uint(f) >> 24) & 0x80u;
    unsigned b = __float_as_uint(fabsf(f) * 0x1p-120f);
    b = b + 0x7FFFFu + ((b >> 20) & 1u);
    unsigned m = b >> 20;
    if (m > 0x7Eu) m = 0x7Eu;  // clamp to 448, never emit NaN
    return s | m;
}
__device__ __forceinline__ float fp82f_sw(unsigned u) {
    unsigned bits = ((u & 0x7Fu) << 20) | ((u & 0x80u) << 24);
    return __uint_as_float(bits) * 0x1p120f;
}
__device__ __forceinline__ void fp8x4_decode(unsigned w, float& r0, float& r1,
                                             float& r2, float& r3) {
#if __has_builtin(__builtin_amdgcn_cvt_pk_f32_fp8)
    f32x2 lo = __builtin_amdgcn_cvt_pk_f32_fp8((int)w, false);
    f32x2 hi = __builtin_amdgcn_cvt_pk_f32_fp8((int)w, true);
    r0 = lo[0]; r1 = lo[1]; r2 = hi[0]; r3 = hi[1];
#else
    r0 = fp82f_sw(w & 0xFFu);
    r1 = fp82f_sw((w >> 8) & 0xFFu);
    r2 = fp82f_sw((w >> 16) & 0xFFu);
    r3 = fp82f_sw(w >> 24);
#endif
}

// ---- fp4 e2m1 helpers (values pre-scaled by 8 at encode) ----
#if !HAVE_HW_FP4
__device__ __forceinline__ unsigned fp4enc_sw(float v) {
    unsigned s = (v < 0.f) ? 8u : 0u;
    float a = fabsf(v);
    unsigned c;
    if (a < 0.25f) c = 0;
    else if (a < 0.75f) c = 1;
    else if (a < 1.25f) c = 2;
    else if (a < 1.75f) c = 3;
    else if (a < 2.5f) c = 4;
    else if (a < 3.5f) c = 5;
    else if (a < 5.0f) c = 6;
    else c = 7;
    return s | c;
}
__device__ __forceinline__ float fp4dec_sw(unsigned nib) {
    unsigned s = nib >> 3, em = nib & 7, e = em >> 1, m = em & 1;
    float mag = (e == 0) ? 0.5f * (float)m
                         : __uint_as_float(((e - 1 + 127) << 23) | (m << 22));
    return s ? -mag : mag;
}
#endif
__device__ __forceinline__ void fp4x2_decode(unsigned w, int sel, float& r0, float& r1) {
#if HAVE_HW_FP4
    f32x2 r = (sel == 0) ? __builtin_amdgcn_cvt_scalef32_pk_f32_fp4(w, 1.0f, 0)
                         : __builtin_amdgcn_cvt_scalef32_pk_f32_fp4(w, 1.0f, 1);
    r0 = r[0]; r1 = r[1];
#else
    unsigned b = (w >> (8 * sel)) & 0xFFu;
    r0 = fp4dec_sw(b & 0xFu);
    r1 = fp4dec_sw(b >> 4);
#endif
}

// ---- binAB: block = (phase, chunk). LDS counting sort of one chunk by
// (dst|src)>>8; staged in LDS, written out coalesced. Meta transposed.
// payloads: binned=((dst&255)<<17)|src, binned2=((src&255)<<17)|dst.
__global__ __launch_bounds__(256) void binAB_kernel(
    const int* __restrict__ src, const int* __restrict__ dst, int E, int NB, int NC,
    unsigned* __restrict__ binned, int* __restrict__ startsT, int* __restrict__ countsT,
    unsigned* __restrict__ binned2, int* __restrict__ startsT2, int* __restrict__ countsT2,
    unsigned* __restrict__ btot) {
    __shared__ unsigned hist[1024];
    __shared__ unsigned scan[1024];
    __shared__ unsigned part[256];
    __shared__ unsigned stage[CHUNK];
    int t = threadIdx.x;
    int ph = blockIdx.x & 1;
    int c = blockIdx.x >> 1;
    int e0 = c * CHUNK;
    int len = min(CHUNK, E - e0);
    const int* key = ph ? src : dst;
    const int* val = ph ? dst : src;
    for (int i = t; i < 1024; i += 256) hist[i] = 0;
    __syncthreads();
    for (int i = t; i < len; i += 256)
        atomicAdd(&hist[key[e0 + i] >> 8], 1u);
    __syncthreads();
    unsigned v0 = hist[4 * t], v1 = hist[4 * t + 1], v2 = hist[4 * t + 2], v3 = hist[4 * t + 3];
    unsigned sum = v0 + v1 + v2 + v3;
    part[t] = sum;
    __syncthreads();
    for (int st = 1; st < 256; st <<= 1) {
        unsigned a = part[t];
        unsigned bl = (t >= st) ? part[t - st] : 0u;
        __syncthreads();
        part[t] = a + bl;
        __syncthreads();
    }
    unsigned base = part[t] - sum;
    scan[4 * t]     = base;
    scan[4 * t + 1] = base + v0;
    scan[4 * t + 2] = base + v0 + v1;
    scan[4 * t + 3] = base + v0 + v1 + v2;
    __syncthreads();
    int* cT = ph ? countsT2 : countsT;
    int* sT = ph ? startsT2 : startsT;
    for (int b = t; b < NB; b += 256) {
        unsigned cnt = hist[b];
        cT[(size_t)c * NB + b] = (int)cnt;
        sT[(size_t)c * NB + b] = e0 + (int)scan[b];
        if (!ph && cnt) atomicAdd(&btot[b], cnt);
    }
    for (int i = t; i < len; i += 256) {
        int k = key[e0 + i];
        int v = val[e0 + i];
        unsigned pos = atomicAdd(&scan[k >> 8], 1u);
        stage[pos] = ((unsigned)(k & 255) << 17) | (unsigned)v;
    }
    __syncthreads();
    unsigned* outp = ph ? binned2 : binned;
    for (int i = t; i < len; i += 256) outp[e0 + i] = stage[i];
}

// ---- bscan: exclusive scan of per-bucket totals -> bstart[NB+1] ----
__global__ __launch_bounds__(256) void bscan_kernel(const unsigned* __restrict__ btot,
                                                    int* __restrict__ bstart, int NB) {
    __shared__ unsigned part[256];
    int t = threadIdx.x;
    unsigned v[4];
    unsigned sum = 0;
    for (int i = 0; i < 4; ++i) {
        int idx = 4 * t + i;
        v[i] = (idx < NB) ? btot[idx] : 0u;
        sum += v[i];
    }
    part[t] = sum;
    __syncthreads();
    for (int st = 1; st < 256; st <<= 1) {
        unsigned a = part[t];
        unsigned bl = (t >= st) ? part[t - st] : 0u;
        __syncthreads();
        part[t] = a + bl;
        __syncthreads();
    }
    unsigned run = part[t] - sum;
    for (int i = 0; i < 4; ++i) {
        int idx = 4 * t + i;
        if (idx < NB) bstart[idx] = (int)run;
        run += v[i];
    }
    if (t == 255) bstart[NB] = (int)run;
}

// ---- compact2: per-bucket (256 nodes) per-node counting sort; 16-lane subgroups ----
__global__ __launch_bounds__(256) void compact2_kernel(
    const unsigned* __restrict__ binned, const int* __restrict__ startsT,
    const int* __restrict__ countsT, const int* __restrict__ bstart,
    int N, int NB, int NC, int E, unsigned* __restrict__ ebkt, int* __restrict__ off,
    float* __restrict__ dinv) {
    __shared__ unsigned cnt[BNODES];
    __shared__ unsigned sc[BNODES];
    __shared__ unsigned cur[BNODES];
    __shared__ int sS[256], sC[256];  // NC <= 256
    int t = threadIdx.x;
    int b = blockIdx.x;
    cnt[t] = 0;
    if (t < NC) { sS[t] = startsT[(size_t)t * NB + b]; sC[t] = countsT[(size_t)t * NB + b]; }
    __syncthreads();
    int sg = t >> 4, sl = t & 15;  // 16 subgroups of 16 lanes
    for (int c = sg; c < NC; c += 16) {
        int s0 = sS[c], len = sC[c];
        for (int o = sl; o < len; o += 16)
            atomicAdd(&cnt[binned[s0 + o] >> 17], 1u);
    }
    __syncthreads();
    sc[t] = cnt[t];
    __syncthreads();
    for (int st = 1; st < BNODES; st <<= 1) {
        unsigned v = sc[t];
        if (t >= st) v += sc[t - st];
        __syncthreads();
        sc[t] = v;
        __syncthreads();
    }
    int dbase = bstart[b];
    {
        unsigned excl = sc[t] - cnt[t];
        cur[t] = excl;
        int n = b * BNODES + t;
        if (n < N) {
            off[n] = dbase + (int)excl;
            dinv[n] = rsqrtf((float)cnt[t] + 1.0f);
        }
    }
    if (b == 0 && t == 0) off[N] = E;
    __syncthreads();
    for (int c = sg; c < NC; c += 16) {
        int s0 = sS[c], len = sC[c];
        for (int o = sl; o < len; o += 16) {
            unsigned ent = binned[s0 + o];
            unsigned pos = atomicAdd(&cur[ent >> 17], 1u);
            ebkt[dbase + (int)pos] = ent;
        }
    }
}

// ---- wsumk: per src-bucket (256 nodes); LDS-accumulate wsum -> coef2 ----
// coef2[n] = {dinv_n, dinv_n * (wsum_n + dinv_n)}
__global__ __launch_bounds__(256) void wsumk_kernel(
    const unsigned* __restrict__ binned2, const int* __restrict__ startsT2,
    const int* __restrict__ countsT2, const float* __restrict__ dinv,
    float2* __restrict__ coef2, int N, int NB, int NC) {
    __shared__ float wsl[BNODES];
    __shared__ int sS[256], sC[256];  // NC <= 256
    int t = threadIdx.x;
    int b = blockIdx.x;
    wsl[t] = 0.f;
    if (t < NC) { sS[t] = startsT2[(size_t)t * NB + b]; sC[t] = countsT2[(size_t)t * NB + b]; }
    __syncthreads();
    int sg = t >> 4, sl = t & 15;
    for (int c = sg; c < NC; c += 16) {
        int s0 = sS[c], len = sC[c];
        for (int o = sl; o < len; o += 16) {
            unsigned ent = binned2[s0 + o];
            atomicAdd(&wsl[ent >> 17], dinv[ent & 0x1FFFFu]);
        }
    }
    __syncthreads();
    {
        int n = b * BNODES + t;
        if (n < N) {
            float di = dinv[n];
            coef2[n] = make_float2(di, di * (wsl[t] + di));
        }
    }
}

// ---- gemm1 (MFMA): xws8 = fp8(dinv * (x @ W1)) ----
__global__ __launch_bounds__(256) void gemm1_kernel(
    const float* __restrict__ x, const float* __restrict__ W,
    const float* __restrict__ dinv, unsigned char* __restrict__ xws8, int N) {
    int t = threadIdx.x;
    int lane = t & 63;
    int n16 = lane & 15;
    int quad = lane >> 4;
    bf16x8 bf[4][2];
#pragma unroll
    for (int cg = 0; cg < 4; ++cg)
#pragma unroll
        for (int kh = 0; kh < 2; ++kh)
#pragma unroll
            for (int j = 0; j < 8; ++j)
                bf[cg][kh][j] = (short)f2bf(W[(kh * 32 + quad * 8 + j) * 64 + cg * 16 + n16]);
    int tiles = (N + 15) >> 4;
    int wave = (blockIdx.x * blockDim.x + t) >> 6;
    int nw = (gridDim.x * blockDim.x) >> 6;
    for (int tile = wave; tile < tiles; tile += nw) {
        int nbase = tile << 4;
        int m = nbase + n16;
        bf16x8 af[2];
        if (m < N) {
            const float* xr = x + (size_t)m * C1;
#pragma unroll
            for (int kh = 0; kh < 2; ++kh) {
                float4 p0 = *(const float4*)(xr + kh * 32 + quad * 8);
                float4 p1 = *(const float4*)(xr + kh * 32 + quad * 8 + 4);
                af[kh][0] = (short)f2bf(p0.x); af[kh][1] = (short)f2bf(p0.y);
                af[kh][2] = (short)f2bf(p0.z); af[kh][3] = (short)f2bf(p0.w);
                af[kh][4] = (short)f2bf(p1.x); af[kh][5] = (short)f2bf(p1.y);
                af[kh][6] = (short)f2bf(p1.z); af[kh][7] = (short)f2bf(p1.w);
            }
        } else {
            af[0] = (bf16x8)(short)0;
            af[1] = (bf16x8)(short)0;
        }
        f32x4 acc[4];
#pragma unroll
        for (int cg = 0; cg < 4; ++cg) {
            acc[cg] = (f32x4)0.f;
            acc[cg] = __builtin_amdgcn_mfma_f32_16x16x32_bf16(af[0], bf[cg][0], acc[cg], 0, 0, 0);
            acc[cg] = __builtin_amdgcn_mfma_f32_16x16x32_bf16(af[1], bf[cg][1], acc[cg], 0, 0, 0);
        }
        int r0 = nbase + quad * 4;
#pragma unroll
        for (int reg = 0; reg < 4; ++reg) {
            int row = r0 + reg;
            if (row < N) {
                float dvr = dinv[row];
                unsigned char* orow = xws8 + (size_t)row * C1 + n16;
#pragma unroll
                for (int cg = 0; cg < 4; ++cg)
                    orow[cg * 16] = (unsigned char)f2fp8(dvr * acc[cg][reg]);
            }
        }
    }
}

// ---- packfp4: fp8 table (6.4MB) -> fp4 table (3.2MB), values pre-scaled x8 ----
__global__ __launch_bounds__(256) void packfp4_kernel(
    const unsigned* __restrict__ xws8w, unsigned* __restrict__ xws4w, int nwords) {
    int i = blockIdx.x * 256 + threadIdx.x;
    if (i >= nwords) return;
    unsigned w0 = xws8w[2 * i], w1 = xws8w[2 * i + 1];
    float v0, v1, v2, v3, v4, v5, v6, v7;
    fp8x4_decode(w0, v0, v1, v2, v3);
    fp8x4_decode(w1, v4, v5, v6, v7);
#if HAVE_HW_FP4
    unsigned u = 0;
    u = __builtin_amdgcn_cvt_scalef32_pk_fp4_f32(u, 8.f * v0, 8.f * v1, 1.0f, 0);
    u = __builtin_amdgcn_cvt_scalef32_pk_fp4_f32(u, 8.f * v2, 8.f * v3, 1.0f, 1);
    u = __builtin_amdgcn_cvt_scalef32_pk_fp4_f32(u, 8.f * v4, 8.f * v5, 1.0f, 2);
    u = __builtin_amdgcn_cvt_scalef32_pk_fp4_f32(u, 8.f * v6, 8.f * v7, 1.0f, 3);
#else
    unsigned u = fp4enc_sw(8.f * v0) | (fp4enc_sw(8.f * v1) << 4)
               | (fp4enc_sw(8.f * v2) << 8) | (fp4enc_sw(8.f * v3) << 12)
               | (fp4enc_sw(8.f * v4) << 16) | (fp4enc_sw(8.f * v5) << 20)
               | (fp4enc_sw(8.f * v6) << 24) | (fp4enc_sw(8.f * v7) << 28);
#endif
    xws4w[i] = u;
}

// ---- gather1g: quarter-slot per node; fp4 gather + relu + weighted reduce ----
__global__ __launch_bounds__(256) void gather1g_kernel(
    const unsigned short* __restrict__ xws4h, const unsigned* __restrict__ ep,
    const int* __restrict__ off, const float2* __restrict__ coef2,
    const float* __restrict__ b1, float* __restrict__ partial, int N) {
    int t = threadIdx.x;
    int lane = t & 63;
    int c4 = t & 15;
    int n = (blockIdx.x * 256 + t) >> 4;  // slot == node
    float4 bb = ((const float4*)b1)[c4];
    float p0 = 0.f, p1 = 0.f, p2 = 0.f, p3 = 0.f;
    if (n < N) {
        unsigned sw = (unsigned)xws4h[(size_t)n * 16 + c4];
        float2 cf = coef2[n];
        int e0 = off[n], e1 = off[n + 1];
        float a0 = 0.f, a1 = 0.f, a2 = 0.f, a3 = 0.f;
        for (int e = e0; e < e1; e += 16) {
            int m = e1 - e;
            int idx = e + c4;
            unsigned ent = (idx < e1) ? ep[idx] : 0u;
#pragma unroll
            for (int j = 0; j < 16; ++j) {
                unsigned ej = __shfl(ent, (lane & 48) | j);
                if (j < m) {
                    unsigned w = (unsigned)xws4h[(size_t)(ej & 0x1FFFFu) * 16 + c4];
                    float v0, v1, v2, v3;
                    fp4x2_decode(w, 0, v0, v1);
                    fp4x2_decode(w, 1, v2, v3);
                    a0 += v0; a1 += v1; a2 += v2; a3 += v3;
                }
            }
        }
        float di = cf.x, wt = cf.y;
        float s0, s1, s2, s3;
        fp4x2_decode(sw, 0, s0, s1);
        fp4x2_decode(sw, 1, s2, s3);
        float dq = di * 0.125f;  // undo the 8x encode scale once
        p0 = wt * fmaxf(dq * (a0 + s0) + bb.x, 0.f);
        p1 = wt * fmaxf(dq * (a1 + s1) + bb.y, 0.f);
        p2 = wt * fmaxf(dq * (a2 + s2) + bb.z, 0.f);
        p3 = wt * fmaxf(dq * (a3 + s3) + bb.w, 0.f);
    }
    __shared__ float red[256][4];
    red[t][0] = p0; red[t][1] = p1; red[t][2] = p2; red[t][3] = p3;
    __syncthreads();
    if (t < 64) {
        int c4r = t >> 2, q = t & 3;
        float s = 0.f;
#pragma unroll
        for (int k = 0; k < 16; ++k) s += red[c4r + 16 * k][q];
        partial[(size_t)blockIdx.x * 64 + t] = s;
    }
}

// ---- reduceK: column-sum partial[nrows][64] -> pooled64 (pre-zeroed) ----
__global__ __launch_bounds__(256) void reduceK_kernel(const float* __restrict__ partial,
                                                      float* __restrict__ pooled64, int nrows) {
    int t = threadIdx.x;
    int ch = t & 63, rs = t >> 6;
    int r0 = blockIdx.x * 98, r1 = min(nrows, r0 + 98);
    float p = 0.f;
    for (int r = r0 + rs; r < r1; r += 4) p += partial[(size_t)r * 64 + ch];
    __shared__ float red[4][64];
    red[rs][ch] = p;
    __syncthreads();
    if (t < 64) atomicAdd(&pooled64[t], red[0][t] + red[1][t] + red[2][t] + red[3][t]);
}

// ---- final: pooled64 @ W2 / N + b2, log_softmax over 32 classes ----
__global__ void final_kernel(const float* __restrict__ pooled64,
                             const float* __restrict__ W2,
                             const float* __restrict__ b2, int N,
                             float* __restrict__ out) {
    int c = threadIdx.x & 31;
    float acc = 0.f;
#pragma unroll
    for (int k = 0; k < 64; ++k) acc += pooled64[k] * W2[k * 32 + c];
    float v = acc / (float)N + b2[c];
    float m = v;
    for (int off = 16; off; off >>= 1) m = fmaxf(m, __shfl_xor(m, off));
    float s = __expf(v - m);
    for (int off = 16; off; off >>= 1) s += __shfl_xor(s, off);
    if (threadIdx.x < 32) out[c] = v - m - logf(s);
}

extern "C" void kernel_launch(void* const* d_in, const int* in_sizes, int n_in,
                              void* d_out, int out_size, void* d_ws, size_t ws_size,
                              hipStream_t stream) {
    const float* x  = (const float*)d_in[0];
    const int*   ei = (const int*)d_in[1];
    const float* W1 = (const float*)d_in[2];
    const float* b1 = (const float*)d_in[3];
    const float* W2 = (const float*)d_in[4];
    const float* b2 = (const float*)d_in[5];
    float* out = (float*)d_out;

    int N = in_sizes[0] / C1;
    int E = in_sizes[1] / 2;
    const int* src = ei;
    const int* dst = ei + E;
    int NB = (N + BNODES - 1) / BNODES;   // 391
    int NC = (E + CHUNK - 1) / CHUNK;     // 131 (<= 256)
    int g1blocks = (N + 15) / 16;         // 6250 (slot == node)
    int nwords4 = N * 8;                  // fp4 table words

    char* ws = (char*)d_ws;
    size_t o = 0;
    auto alloc = [&](size_t bytes) { void* p = ws + o; o = (o + bytes + 255) & ~(size_t)255; return p; };
    unsigned*      btot     = (unsigned*)alloc((size_t)(NB + 1) * 4);
    int*           bstart   = (int*)alloc((size_t)(NB + 1) * 4);
    int*           startsT  = (int*)alloc((size_t)NC * NB * 4);
    int*           countsT  = (int*)alloc((size_t)NC * NB * 4);
    int*           startsT2 = (int*)alloc((size_t)NC * NB * 4);
    int*           countsT2 = (int*)alloc((size_t)NC * NB * 4);
    float*         dinv     = (float*)alloc((size_t)N * 4);
    int*           off      = (int*)alloc((size_t)(N + 1) * 4);
    float2*        coef2    = (float2*)alloc((size_t)N * 8);
    float*         pooled64 = (float*)alloc(64 * 4);
    unsigned*      binned   = (unsigned*)alloc((size_t)E * 4);
    unsigned*      binned2  = (unsigned*)alloc((size_t)E * 4);
    unsigned*      ebkt     = (unsigned*)alloc((size_t)E * 4);
    unsigned char* xws8     = (unsigned char*)alloc((size_t)N * C1);
    unsigned*      xws4     = (unsigned*)alloc((size_t)nwords4 * 4);
    float*         partial  = (float*)alloc((size_t)g1blocks * 64 * 4);

    hipMemsetAsync(btot, 0, (size_t)(NB + 1) * 4, stream);
    hipMemsetAsync(pooled64, 0, 64 * 4, stream);

    binAB_kernel<<<NC * 2, 256, 0, stream>>>(src, dst, E, NB, NC, binned, startsT, countsT,
                                             binned2, startsT2, countsT2, btot);
    bscan_kernel<<<1, 256, 0, stream>>>(btot, bstart, NB);
    compact2_kernel<<<NB, 256, 0, stream>>>(binned, startsT, countsT, bstart, N, NB, NC, E,
                                            ebkt, off, dinv);
    wsumk_kernel<<<NB, 256, 0, stream>>>(binned2, startsT2, countsT2, dinv, coef2, N, NB, NC);
    gemm1_kernel<<<256, 256, 0, stream>>>(x, W1, dinv, xws8, N);
    packfp4_kernel<<<(nwords4 + 255) / 256, 256, 0, stream>>>((const unsigned*)xws8, xws4,
                                                              nwords4);
    gather1g_kernel<<<g1blocks, 256, 0, stream>>>((const unsigned short*)xws4, ebkt, off,
                                                  coef2, b1, partial, N);
    reduceK_kernel<<<(g1blocks + 97) / 98, 256, 0, stream>>>(partial, pooled64, g1blocks);
    final_kernel<<<1, 64, 0, stream>>>(pooled64, W2, b2, N, out);
}

// Round 19
// 207.306 us; speedup vs baseline: 1.0300x; 1.0300x over previous
//
#include <hip/hip_runtime.h>
#include <math.h>

// GCN 2-layer, N nodes, E edges, 64 -> 64 -> 32 channels.
// R19 = R17 (CHUNK 8192 / BNODES 128 -- R18's bigger buckets regressed) with
// bscan folded into compact2 (each block sums btot[0..b) itself; one fewer
// launch + dependency bubble).
//   pooled = (1/N) * Sum_s c_s * relu(out1_s + b1) @ W2 + b2
//   c_s = dinv_s * (wsum_s + dinv_s),  wsum_s = Sum_{e: src=s} dinv[dst_e]

#define C1 64
#define C2 32
#define CHUNK 8192
#define BNODES 128

typedef __attribute__((ext_vector_type(8))) short bf16x8;
typedef __attribute__((ext_vector_type(4))) float f32x4;
typedef __attribute__((ext_vector_type(2))) float f32x2;

#if __has_builtin(__builtin_amdgcn_cvt_scalef32_pk_f32_fp4) && \
    __has_builtin(__builtin_amdgcn_cvt_scalef32_pk_fp4_f32)
#define HAVE_HW_FP4 1
#else
#define HAVE_HW_FP4 0
#endif

__device__ __forceinline__ unsigned short f2bf(float f) {
    unsigned u = __float_as_uint(f);
    u = (u + 0x7FFFu + ((u >> 16) & 1u)) >> 16;
    return (unsigned short)u;
}
// ---- fp8 e4m3fn (OCP) software encode (exact bit pattern) ----
__device__ __forceinline__ unsigned f2fp8(float f) {
    unsigned s = (__float_as_uint(f) >> 24) & 0x80u;
    unsigned b = __float_as_uint(fabsf(f) * 0x1p-120f);
    b = b + 0x7FFFFu + ((b >> 20) & 1u);
    unsigned m = b >> 20;
    if (m > 0x7Eu) m = 0x7Eu;  // clamp to 448, never emit NaN
    return s | m;
}
__device__ __forceinline__ float fp82f_sw(unsigned u) {
    unsigned bits = ((u & 0x7Fu) << 20) | ((u & 0x80u) << 24);
    return __uint_as_float(bits) * 0x1p120f;
}
__device__ __forceinline__ void fp8x4_decode(unsigned w, float& r0, float& r1,
                                             float& r2, float& r3) {
#if __has_builtin(__builtin_amdgcn_cvt_pk_f32_fp8)
    f32x2 lo = __builtin_amdgcn_cvt_pk_f32_fp8((int)w, false);
    f32x2 hi = __builtin_amdgcn_cvt_pk_f32_fp8((int)w, true);
    r0 = lo[0]; r1 = lo[1]; r2 = hi[0]; r3 = hi[1];
#else
    r0 = fp82f_sw(w & 0xFFu);
    r1 = fp82f_sw((w >> 8) & 0xFFu);
    r2 = fp82f_sw((w >> 16) & 0xFFu);
    r3 = fp82f_sw(w >> 24);
#endif
}

// ---- fp4 e2m1 helpers (values pre-scaled by 8 at encode) ----
#if !HAVE_HW_FP4
__device__ __forceinline__ unsigned fp4enc_sw(float v) {
    unsigned s = (v < 0.f) ? 8u : 0u;
    float a = fabsf(v);
    unsigned c;
    if (a < 0.25f) c = 0;
    else if (a < 0.75f) c = 1;
    else if (a < 1.25f) c = 2;
    else if (a < 1.75f) c = 3;
    else if (a < 2.5f) c = 4;
    else if (a < 3.5f) c = 5;
    else if (a < 5.0f) c = 6;
    else c = 7;
    return s | c;
}
__device__ __forceinline__ float fp4dec_sw(unsigned nib) {
    unsigned s = nib >> 3, em = nib & 7, e = em >> 1, m = em & 1;
    float mag = (e == 0) ? 0.5f * (float)m
                         : __uint_as_float(((e - 1 + 127) << 23) | (m << 22));
    return s ? -mag : mag;
}
#endif
__device__ __forceinline__ void fp4x2_decode(unsigned w, int sel, float& r0, float& r1) {
#if HAVE_HW_FP4
    f32x2 r = (sel == 0) ? __builtin_amdgcn_cvt_scalef32_pk_f32_fp4(w, 1.0f, 0)
                         : __builtin_amdgcn_cvt_scalef32_pk_f32_fp4(w, 1.0f, 1);
    r0 = r[0]; r1 = r[1];
#else
    unsigned b = (w >> (8 * sel)) & 0xFFu;
    r0 = fp4dec_sw(b & 0xFu);
    r1 = fp4dec_sw(b >> 4);
#endif
}

// ---- binAB: block = (phase, chunk). LDS counting sort of one 8192-edge chunk
// by (dst|src)>>7; staged in LDS, written out coalesced. Meta transposed.
// payloads: binned=(dst_local<<17)|src, binned2=(src_local<<17)|dst.
__global__ __launch_bounds__(256) void binAB_kernel(
    const int* __restrict__ src, const int* __restrict__ dst, int E, int NB, int NC,
    unsigned* __restrict__ binned, int* __restrict__ startsT, int* __restrict__ countsT,
    unsigned* __restrict__ binned2, int* __restrict__ startsT2, int* __restrict__ countsT2,
    unsigned* __restrict__ btot) {
    __shared__ unsigned hist[1024];
    __shared__ unsigned scan[1024];
    __shared__ unsigned part[256];
    __shared__ unsigned stage[CHUNK];
    int t = threadIdx.x;
    int ph = blockIdx.x & 1;
    int c = blockIdx.x >> 1;
    int e0 = c * CHUNK;
    int len = min(CHUNK, E - e0);
    const int* key = ph ? src : dst;
    const int* val = ph ? dst : src;
    for (int i = t; i < 1024; i += 256) hist[i] = 0;
    __syncthreads();
    for (int i = t; i < len; i += 256)
        atomicAdd(&hist[key[e0 + i] >> 7], 1u);
    __syncthreads();
    unsigned v0 = hist[4 * t], v1 = hist[4 * t + 1], v2 = hist[4 * t + 2], v3 = hist[4 * t + 3];
    unsigned sum = v0 + v1 + v2 + v3;
    part[t] = sum;
    __syncthreads();
    for (int st = 1; st < 256; st <<= 1) {
        unsigned a = part[t];
        unsigned bl = (t >= st) ? part[t - st] : 0u;
        __syncthreads();
        part[t] = a + bl;
        __syncthreads();
    }
    unsigned base = part[t] - sum;
    scan[4 * t]     = base;
    scan[4 * t + 1] = base + v0;
    scan[4 * t + 2] = base + v0 + v1;
    scan[4 * t + 3] = base + v0 + v1 + v2;
    __syncthreads();
    int* cT = ph ? countsT2 : countsT;
    int* sT = ph ? startsT2 : startsT;
    for (int b = t; b < NB; b += 256) {
        unsigned cnt = hist[b];
        cT[(size_t)c * NB + b] = (int)cnt;
        sT[(size_t)c * NB + b] = e0 + (int)scan[b];
        if (!ph && cnt) atomicAdd(&btot[b], cnt);
    }
    for (int i = t; i < len; i += 256) {
        int k = key[e0 + i];
        int v = val[e0 + i];
        unsigned pos = atomicAdd(&scan[k >> 7], 1u);
        stage[pos] = ((unsigned)(k & 127) << 17) | (unsigned)v;
    }
    __syncthreads();
    unsigned* outp = ph ? binned2 : binned;
    for (int i = t; i < len; i += 256) outp[e0 + i] = stage[i];
}

// ---- compact2: per-bucket per-node counting sort; 16-lane subgroups.
// Computes its own bstart[b] = sum(btot[0..b)) (bscan folded in). ----
__global__ __launch_bounds__(256) void compact2_kernel(
    const unsigned* __restrict__ binned, const int* __restrict__ startsT,
    const int* __restrict__ countsT, const unsigned* __restrict__ btot,
    int N, int NB, int NC, int E, unsigned* __restrict__ ebkt, int* __restrict__ off,
    float* __restrict__ dinv) {
    __shared__ unsigned cnt[BNODES];
    __shared__ unsigned sc[BNODES];
    __shared__ unsigned cur[BNODES];
    __shared__ int sS[256], sC[256];
    __shared__ unsigned pre[256];
    int t = threadIdx.x;
    int b = blockIdx.x;
    if (t < BNODES) cnt[t] = 0;
    if (t < NC) { sS[t] = startsT[(size_t)t * NB + b]; sC[t] = countsT[(size_t)t * NB + b]; }
    // inline prefix: sum btot[0..b) across 256 threads
    {
        unsigned s = 0;
        for (int i = t; i < b; i += 256) s += btot[i];
        pre[t] = s;
        __syncthreads();
        for (int st = 128; st; st >>= 1) {
            if (t < st) pre[t] += pre[t + st];
            __syncthreads();
        }
    }
    int dbase = (int)pre[0];
    __syncthreads();
    int sg = t >> 4, sl = t & 15;  // 16 subgroups of 16 lanes
    for (int c = sg; c < NC; c += 16) {
        int s0 = sS[c], len = sC[c];
        for (int o = sl; o < len; o += 16)
            atomicAdd(&cnt[binned[s0 + o] >> 17], 1u);
    }
    __syncthreads();
    if (t < BNODES) sc[t] = cnt[t];
    __syncthreads();
    for (int st = 1; st < BNODES; st <<= 1) {
        unsigned v = 0;
        if (t < BNODES) { v = sc[t]; if (t >= st) v += sc[t - st]; }
        __syncthreads();
        if (t < BNODES) sc[t] = v;
        __syncthreads();
    }
    if (t < BNODES) {
        unsigned excl = sc[t] - cnt[t];
        cur[t] = excl;
        int n = b * BNODES + t;
        if (n < N) {
            off[n] = dbase + (int)excl;
            dinv[n] = rsqrtf((float)cnt[t] + 1.0f);
        }
    }
    if (b == 0 && t == 0) off[N] = E;
    __syncthreads();
    for (int c = sg; c < NC; c += 16) {
        int s0 = sS[c], len = sC[c];
        for (int o = sl; o < len; o += 16) {
            unsigned ent = binned[s0 + o];
            unsigned pos = atomicAdd(&cur[ent >> 17], 1u);
            ebkt[dbase + (int)pos] = ent;
        }
    }
}

// ---- wsumk: per src-bucket; LDS-accumulate wsum, write coef2 directly ----
// coef2[n] = {dinv_n, dinv_n * (wsum_n + dinv_n)}
__global__ __launch_bounds__(256) void wsumk_kernel(
    const unsigned* __restrict__ binned2, const int* __restrict__ startsT2,
    const int* __restrict__ countsT2, const float* __restrict__ dinv,
    float2* __restrict__ coef2, int N, int NB, int NC) {
    __shared__ float wsl[BNODES];
    __shared__ int sS[256], sC[256];
    int t = threadIdx.x;
    int b = blockIdx.x;
    if (t < BNODES) wsl[t] = 0.f;
    if (t < NC) { sS[t] = startsT2[(size_t)t * NB + b]; sC[t] = countsT2[(size_t)t * NB + b]; }
    __syncthreads();
    int sg = t >> 4, sl = t & 15;
    for (int c = sg; c < NC; c += 16) {
        int s0 = sS[c], len = sC[c];
        for (int o = sl; o < len; o += 16) {
            unsigned ent = binned2[s0 + o];
            atomicAdd(&wsl[ent >> 17], dinv[ent & 0x1FFFFu]);
        }
    }
    __syncthreads();
    if (t < BNODES) {
        int n = b * BNODES + t;
        if (n < N) {
            float di = dinv[n];
            coef2[n] = make_float2(di, di * (wsl[t] + di));
        }
    }
}

// ---- gemm1 (MFMA): xws8 = fp8(dinv * (x @ W1)) ----
__global__ __launch_bounds__(256) void gemm1_kernel(
    const float* __restrict__ x, const float* __restrict__ W,
    const float* __restrict__ dinv, unsigned char* __restrict__ xws8, int N) {
    int t = threadIdx.x;
    int lane = t & 63;
    int n16 = lane & 15;
    int quad = lane >> 4;
    bf16x8 bf[4][2];
#pragma unroll
    for (int cg = 0; cg < 4; ++cg)
#pragma unroll
        for (int kh = 0; kh < 2; ++kh)
#pragma unroll
            for (int j = 0; j < 8; ++j)
                bf[cg][kh][j] = (short)f2bf(W[(kh * 32 + quad * 8 + j) * 64 + cg * 16 + n16]);
    int tiles = (N + 15) >> 4;
    int wave = (blockIdx.x * blockDim.x + t) >> 6;
    int nw = (gridDim.x * blockDim.x) >> 6;
    for (int tile = wave; tile < tiles; tile += nw) {
        int nbase = tile << 4;
        int m = nbase + n16;
        bf16x8 af[2];
        if (m < N) {
            const float* xr = x + (size_t)m * C1;
#pragma unroll
            for (int kh = 0; kh < 2; ++kh) {
                float4 p0 = *(const float4*)(xr + kh * 32 + quad * 8);
                float4 p1 = *(const float4*)(xr + kh * 32 + quad * 8 + 4);
                af[kh][0] = (short)f2bf(p0.x); af[kh][1] = (short)f2bf(p0.y);
                af[kh][2] = (short)f2bf(p0.z); af[kh][3] = (short)f2bf(p0.w);
                af[kh][4] = (short)f2bf(p1.x); af[kh][5] = (short)f2bf(p1.y);
                af[kh][6] = (short)f2bf(p1.z); af[kh][7] = (short)f2bf(p1.w);
            }
        } else {
            af[0] = (bf16x8)(short)0;
            af[1] = (bf16x8)(short)0;
        }
        f32x4 acc[4];
#pragma unroll
        for (int cg = 0; cg < 4; ++cg) {
            acc[cg] = (f32x4)0.f;
            acc[cg] = __builtin_amdgcn_mfma_f32_16x16x32_bf16(af[0], bf[cg][0], acc[cg], 0, 0, 0);
            acc[cg] = __builtin_amdgcn_mfma_f32_16x16x32_bf16(af[1], bf[cg][1], acc[cg], 0, 0, 0);
        }
        int r0 = nbase + quad * 4;
#pragma unroll
        for (int reg = 0; reg < 4; ++reg) {
            int row = r0 + reg;
            if (row < N) {
                float dvr = dinv[row];
                unsigned char* orow = xws8 + (size_t)row * C1 + n16;
#pragma unroll
                for (int cg = 0; cg < 4; ++cg)
                    orow[cg * 16] = (unsigned char)f2fp8(dvr * acc[cg][reg]);
            }
        }
    }
}

// ---- packfp4: fp8 table (6.4MB) -> fp4 table (3.2MB), values pre-scaled x8 ----
__global__ __launch_bounds__(256) void packfp4_kernel(
    const unsigned* __restrict__ xws8w, unsigned* __restrict__ xws4w, int nwords) {
    int i = blockIdx.x * 256 + threadIdx.x;
    if (i >= nwords) return;
    unsigned w0 = xws8w[2 * i], w1 = xws8w[2 * i + 1];
    float v0, v1, v2, v3, v4, v5, v6, v7;
    fp8x4_decode(w0, v0, v1, v2, v3);
    fp8x4_decode(w1, v4, v5, v6, v7);
#if HAVE_HW_FP4
    unsigned u = 0;
    u = __builtin_amdgcn_cvt_scalef32_pk_fp4_f32(u, 8.f * v0, 8.f * v1, 1.0f, 0);
    u = __builtin_amdgcn_cvt_scalef32_pk_fp4_f32(u, 8.f * v2, 8.f * v3, 1.0f, 1);
    u = __builtin_amdgcn_cvt_scalef32_pk_fp4_f32(u, 8.f * v4, 8.f * v5, 1.0f, 2);
    u = __builtin_amdgcn_cvt_scalef32_pk_fp4_f32(u, 8.f * v6, 8.f * v7, 1.0f, 3);
#else
    unsigned u = fp4enc_sw(8.f * v0) | (fp4enc_sw(8.f * v1) << 4)
               | (fp4enc_sw(8.f * v2) << 8) | (fp4enc_sw(8.f * v3) << 12)
               | (fp4enc_sw(8.f * v4) << 16) | (fp4enc_sw(8.f * v5) << 20)
               | (fp4enc_sw(8.f * v6) << 24) | (fp4enc_sw(8.f * v7) << 28);
#endif
    xws4w[i] = u;
}

// ---- gather1g: quarter-slot per node; fp4 gather + relu + weighted reduce ----
__global__ __launch_bounds__(256) void gather1g_kernel(
    const unsigned short* __restrict__ xws4h, const unsigned* __restrict__ ep,
    const int* __restrict__ off, const float2* __restrict__ coef2,
    const float* __restrict__ b1, float* __restrict__ partial, int N) {
    int t = threadIdx.x;
    int lane = t & 63;
    int c4 = t & 15;
    int n = (blockIdx.x * 256 + t) >> 4;  // slot == node
    float4 bb = ((const float4*)b1)[c4];
    float p0 = 0.f, p1 = 0.f, p2 = 0.f, p3 = 0.f;
    if (n < N) {
        unsigned sw = (unsigned)xws4h[(size_t)n * 16 + c4];
        float2 cf = coef2[n];
        int e0 = off[n], e1 = off[n + 1];
        float a0 = 0.f, a1 = 0.f, a2 = 0.f, a3 = 0.f;
        for (int e = e0; e < e1; e += 16) {
            int m = e1 - e;
            int idx = e + c4;
            unsigned ent = (idx < e1) ? ep[idx] : 0u;
#pragma unroll
            for (int j = 0; j < 16; ++j) {
                unsigned ej = __shfl(ent, (lane & 48) | j);
                if (j < m) {
                    unsigned w = (unsigned)xws4h[(size_t)(ej & 0x1FFFFu) * 16 + c4];
                    float v0, v1, v2, v3;
                    fp4x2_decode(w, 0, v0, v1);
                    fp4x2_decode(w, 1, v2, v3);
                    a0 += v0; a1 += v1; a2 += v2; a3 += v3;
                }
            }
        }
        float di = cf.x, wt = cf.y;
        float s0, s1, s2, s3;
        fp4x2_decode(sw, 0, s0, s1);
        fp4x2_decode(sw, 1, s2, s3);
        float dq = di * 0.125f;  // undo the 8x encode scale once
        p0 = wt * fmaxf(dq * (a0 + s0) + bb.x, 0.f);
        p1 = wt * fmaxf(dq * (a1 + s1) + bb.y, 0.f);
        p2 = wt * fmaxf(dq * (a2 + s2) + bb.z, 0.f);
        p3 = wt * fmaxf(dq * (a3 + s3) + bb.w, 0.f);
    }
    __shared__ float red[256][4];
    red[t][0] = p0; red[t][1] = p1; red[t][2] = p2; red[t][3] = p3;
    __syncthreads();
    if (t < 64) {
        int c4r = t >> 2, q = t & 3;
        float s = 0.f;
#pragma unroll
        for (int k = 0; k < 16; ++k) s += red[c4r + 16 * k][q];
        partial[(size_t)blockIdx.x * 64 + t] = s;
    }
}

// ---- reduceK: column-sum partial[nrows][64] -> pooled64 (pre-zeroed) ----
__global__ __launch_bounds__(256) void reduceK_kernel(const float* __restrict__ partial,
                                                      float* __restrict__ pooled64, int nrows) {
    int t = threadIdx.x;
    int ch = t & 63, rs = t >> 6;
    int r0 = blockIdx.x * 98, r1 = min(nrows, r0 + 98);
    float p = 0.f;
    for (int r = r0 + rs; r < r1; r += 4) p += partial[(size_t)r * 64 + ch];
    __shared__ float red[4][64];
    red[rs][ch] = p;
    __syncthreads();
    if (t < 64) atomicAdd(&pooled64[t], red[0][t] + red[1][t] + red[2][t] + red[3][t]);
}

// ---- final: pooled64 @ W2 / N + b2, log_softmax over 32 classes ----
__global__ void final_kernel(const float* __restrict__ pooled64,
                             const float* __restrict__ W2,
                             const float* __restrict__ b2, int N,
                             float* __restrict__ out) {
    int c = threadIdx.x & 31;
    float acc = 0.f;
#pragma unroll
    for (int k = 0; k < 64; ++k) acc += pooled64[k] * W2[k * 32 + c];
    float v = acc / (float)N + b2[c];
    float m = v;
    for (int off = 16; off; off >>= 1) m = fmaxf(m, __shfl_xor(m, off));
    float s = __expf(v - m);
    for (int off = 16; off; off >>= 1) s += __shfl_xor(s, off);
    if (threadIdx.x < 32) out[c] = v - m - logf(s);
}

extern "C" void kernel_launch(void* const* d_in, const int* in_sizes, int n_in,
                              void* d_out, int out_size, void* d_ws, size_t ws_size,
                              hipStream_t stream) {
    const float* x  = (const float*)d_in[0];
    const int*   ei = (const int*)d_in[1];
    const float* W1 = (const float*)d_in[2];
    const float* b1 = (const float*)d_in[3];
    const float* W2 = (const float*)d_in[4];
    const float* b2 = (const float*)d_in[5];
    float* out = (float*)d_out;

    int N = in_sizes[0] / C1;
    int E = in_sizes[1] / 2;
    const int* src = ei;
    const int* dst = ei + E;
    int NB = (N + BNODES - 1) / BNODES;   // 782
    int NC = (E + CHUNK - 1) / CHUNK;     // 196 (<= 256)
    int g1blocks = (N + 15) / 16;         // 6250 (slot == node)
    int nwords4 = N * 8;                  // fp4 table words

    char* ws = (char*)d_ws;
    size_t o = 0;
    auto alloc = [&](size_t bytes) { void* p = ws + o; o = (o + bytes + 255) & ~(size_t)255; return p; };
    unsigned*      btot     = (unsigned*)alloc((size_t)(NB + 1) * 4);
    int*           startsT  = (int*)alloc((size_t)NC * NB * 4);
    int*           countsT  = (int*)alloc((size_t)NC * NB * 4);
    int*           startsT2 = (int*)alloc((size_t)NC * NB * 4);
    int*           countsT2 = (int*)alloc((size_t)NC * NB * 4);
    float*         dinv     = (float*)alloc((size_t)N * 4);
    int*           off      = (int*)alloc((size_t)(N + 1) * 4);
    float2*        coef2    = (float2*)alloc((size_t)N * 8);
    float*         pooled64 = (float*)alloc(64 * 4);
    unsigned*      binned   = (unsigned*)alloc((size_t)E * 4);
    unsigned*      binned2  = (unsigned*)alloc((size_t)E * 4);
    unsigned*      ebkt     = (unsigned*)alloc((size_t)E * 4);
    unsigned char* xws8     = (unsigned char*)alloc((size_t)N * C1);
    unsigned*      xws4     = (unsigned*)alloc((size_t)nwords4 * 4);
    float*         partial  = (float*)alloc((size_t)g1blocks * 64 * 4);

    hipMemsetAsync(btot, 0, (size_t)(NB + 1) * 4, stream);
    hipMemsetAsync(pooled64, 0, 64 * 4, stream);

    binAB_kernel<<<NC * 2, 256, 0, stream>>>(src, dst, E, NB, NC, binned, startsT, countsT,
                                             binned2, startsT2, countsT2, btot);
    compact2_kernel<<<NB, 256, 0, stream>>>(binned, startsT, countsT, btot, N, NB, NC, E,
                                            ebkt, off, dinv);
    wsumk_kernel<<<NB, 256, 0, stream>>>(binned2, startsT2, countsT2, dinv, coef2, N, NB, NC);
    gemm1_kernel<<<256, 256, 0, stream>>>(x, W1, dinv, xws8, N);
    packfp4_kernel<<<(nwords4 + 255) / 256, 256, 0, stream>>>((const unsigned*)xws8, xws4,
                                                              nwords4);
    gather1g_kernel<<<g1blocks, 256, 0, stream>>>((const unsigned short*)xws4, ebkt, off,
                                                  coef2, b1, partial, N);
    reduceK_kernel<<<(g1blocks + 97) / 98, 256, 0, stream>>>(partial, pooled64, g1blocks);
    final_kernel<<<1, 64, 0, stream>>>(pooled64, W2, b2, N, out);
}

// Round 20
// 202.983 us; speedup vs baseline: 1.0520x; 1.0213x over previous
//
#include <hip/hip_runtime.h>
#include <math.h>

// GCN 2-layer, N nodes, E edges, 64 -> 64 -> 32 channels.
// R20 = R19 with two fusions (8 -> 6 kernels):
//  - gemm1 emits the fp4 table directly (wave-private LDS transpose, no
//    barrier; kills packfp4's launch + 12.8MB traffic + the fp8 buffer).
//  - reduceF = reduceK + final via ticket counter (last block computes
//    log_softmax; pooled64 re-read with device-scope atomicAdd(p, 0.f)).
//   pooled = (1/N) * Sum_s c_s * relu(out1_s + b1) @ W2 + b2
//   c_s = dinv_s * (wsum_s + dinv_s),  wsum_s = Sum_{e: src=s} dinv[dst_e]

#define C1 64
#define C2 32
#define CHUNK 8192
#define BNODES 128

typedef __attribute__((ext_vector_type(8))) short bf16x8;
typedef __attribute__((ext_vector_type(4))) float f32x4;
typedef __attribute__((ext_vector_type(2))) float f32x2;

#if __has_builtin(__builtin_amdgcn_cvt_scalef32_pk_f32_fp4) && \
    __has_builtin(__builtin_amdgcn_cvt_scalef32_pk_fp4_f32)
#define HAVE_HW_FP4 1
#else
#define HAVE_HW_FP4 0
#endif

__device__ __forceinline__ unsigned short f2bf(float f) {
    unsigned u = __float_as_uint(f);
    u = (u + 0x7FFFu + ((u >> 16) & 1u)) >> 16;
    return (unsigned short)u;
}

// ---- fp4 e2m1 helpers (values pre-scaled by 8 at encode) ----
#if !HAVE_HW_FP4
__device__ __forceinline__ unsigned fp4enc_sw(float v) {
    unsigned s = (v < 0.f) ? 8u : 0u;
    float a = fabsf(v);
    unsigned c;
    if (a < 0.25f) c = 0;
    else if (a < 0.75f) c = 1;
    else if (a < 1.25f) c = 2;
    else if (a < 1.75f) c = 3;
    else if (a < 2.5f) c = 4;
    else if (a < 3.5f) c = 5;
    else if (a < 5.0f) c = 6;
    else c = 7;
    return s | c;
}
__device__ __forceinline__ float fp4dec_sw(unsigned nib) {
    unsigned s = nib >> 3, em = nib & 7, e = em >> 1, m = em & 1;
    float mag = (e == 0) ? 0.5f * (float)m
                         : __uint_as_float(((e - 1 + 127) << 23) | (m << 22));
    return s ? -mag : mag;
}
#endif
__device__ __forceinline__ void fp4x2_decode(unsigned w, int sel, float& r0, float& r1) {
#if HAVE_HW_FP4
    f32x2 r = (sel == 0) ? __builtin_amdgcn_cvt_scalef32_pk_f32_fp4(w, 1.0f, 0)
                         : __builtin_amdgcn_cvt_scalef32_pk_f32_fp4(w, 1.0f, 1);
    r0 = r[0]; r1 = r[1];
#else
    unsigned b = (w >> (8 * sel)) & 0xFFu;
    r0 = fp4dec_sw(b & 0xFu);
    r1 = fp4dec_sw(b >> 4);
#endif
}
// encode 8 floats (already in fp4 range after x8 scale) -> one u32, nibble i = ch i
__device__ __forceinline__ unsigned fp4x8_encode(const float* f) {
#if HAVE_HW_FP4
    unsigned u = 0;
    u = __builtin_amdgcn_cvt_scalef32_pk_fp4_f32(u, 8.f * f[0], 8.f * f[1], 1.0f, 0);
    u = __builtin_amdgcn_cvt_scalef32_pk_fp4_f32(u, 8.f * f[2], 8.f * f[3], 1.0f, 1);
    u = __builtin_amdgcn_cvt_scalef32_pk_fp4_f32(u, 8.f * f[4], 8.f * f[5], 1.0f, 2);
    u = __builtin_amdgcn_cvt_scalef32_pk_fp4_f32(u, 8.f * f[6], 8.f * f[7], 1.0f, 3);
    return u;
#else
    return fp4enc_sw(8.f * f[0]) | (fp4enc_sw(8.f * f[1]) << 4)
         | (fp4enc_sw(8.f * f[2]) << 8) | (fp4enc_sw(8.f * f[3]) << 12)
         | (fp4enc_sw(8.f * f[4]) << 16) | (fp4enc_sw(8.f * f[5]) << 20)
         | (fp4enc_sw(8.f * f[6]) << 24) | (fp4enc_sw(8.f * f[7]) << 28);
#endif
}

// ---- binAB: block = (phase, chunk). LDS counting sort of one 8192-edge chunk
// by (dst|src)>>7; staged in LDS, written out coalesced. Meta transposed.
// payloads: binned=(dst_local<<17)|src, binned2=(src_local<<17)|dst.
__global__ __launch_bounds__(256) void binAB_kernel(
    const int* __restrict__ src, const int* __restrict__ dst, int E, int NB, int NC,
    unsigned* __restrict__ binned, int* __restrict__ startsT, int* __restrict__ countsT,
    unsigned* __restrict__ binned2, int* __restrict__ startsT2, int* __restrict__ countsT2,
    unsigned* __restrict__ btot) {
    __shared__ unsigned hist[1024];
    __shared__ unsigned scan[1024];
    __shared__ unsigned part[256];
    __shared__ unsigned stage[CHUNK];
    int t = threadIdx.x;
    int ph = blockIdx.x & 1;
    int c = blockIdx.x >> 1;
    int e0 = c * CHUNK;
    int len = min(CHUNK, E - e0);
    const int* key = ph ? src : dst;
    const int* val = ph ? dst : src;
    for (int i = t; i < 1024; i += 256) hist[i] = 0;
    __syncthreads();
    for (int i = t; i < len; i += 256)
        atomicAdd(&hist[key[e0 + i] >> 7], 1u);
    __syncthreads();
    unsigned v0 = hist[4 * t], v1 = hist[4 * t + 1], v2 = hist[4 * t + 2], v3 = hist[4 * t + 3];
    unsigned sum = v0 + v1 + v2 + v3;
    part[t] = sum;
    __syncthreads();
    for (int st = 1; st < 256; st <<= 1) {
        unsigned a = part[t];
        unsigned bl = (t >= st) ? part[t - st] : 0u;
        __syncthreads();
        part[t] = a + bl;
        __syncthreads();
    }
    unsigned base = part[t] - sum;
    scan[4 * t]     = base;
    scan[4 * t + 1] = base + v0;
    scan[4 * t + 2] = base + v0 + v1;
    scan[4 * t + 3] = base + v0 + v1 + v2;
    __syncthreads();
    int* cT = ph ? countsT2 : countsT;
    int* sT = ph ? startsT2 : startsT;
    for (int b = t; b < NB; b += 256) {
        unsigned cnt = hist[b];
        cT[(size_t)c * NB + b] = (int)cnt;
        sT[(size_t)c * NB + b] = e0 + (int)scan[b];
        if (!ph && cnt) atomicAdd(&btot[b], cnt);
    }
    for (int i = t; i < len; i += 256) {
        int k = key[e0 + i];
        int v = val[e0 + i];
        unsigned pos = atomicAdd(&scan[k >> 7], 1u);
        stage[pos] = ((unsigned)(k & 127) << 17) | (unsigned)v;
    }
    __syncthreads();
    unsigned* outp = ph ? binned2 : binned;
    for (int i = t; i < len; i += 256) outp[e0 + i] = stage[i];
}

// ---- compact2: per-bucket per-node counting sort; 16-lane subgroups.
// Computes its own bstart[b] = sum(btot[0..b)) (bscan folded in). ----
__global__ __launch_bounds__(256) void compact2_kernel(
    const unsigned* __restrict__ binned, const int* __restrict__ startsT,
    const int* __restrict__ countsT, const unsigned* __restrict__ btot,
    int N, int NB, int NC, int E, unsigned* __restrict__ ebkt, int* __restrict__ off,
    float* __restrict__ dinv) {
    __shared__ unsigned cnt[BNODES];
    __shared__ unsigned sc[BNODES];
    __shared__ unsigned cur[BNODES];
    __shared__ int sS[256], sC[256];
    __shared__ unsigned pre[256];
    int t = threadIdx.x;
    int b = blockIdx.x;
    if (t < BNODES) cnt[t] = 0;
    if (t < NC) { sS[t] = startsT[(size_t)t * NB + b]; sC[t] = countsT[(size_t)t * NB + b]; }
    {
        unsigned s = 0;
        for (int i = t; i < b; i += 256) s += btot[i];
        pre[t] = s;
        __syncthreads();
        for (int st = 128; st; st >>= 1) {
            if (t < st) pre[t] += pre[t + st];
            __syncthreads();
        }
    }
    int dbase = (int)pre[0];
    __syncthreads();
    int sg = t >> 4, sl = t & 15;  // 16 subgroups of 16 lanes
    for (int c = sg; c < NC; c += 16) {
        int s0 = sS[c], len = sC[c];
        for (int o = sl; o < len; o += 16)
            atomicAdd(&cnt[binned[s0 + o] >> 17], 1u);
    }
    __syncthreads();
    if (t < BNODES) sc[t] = cnt[t];
    __syncthreads();
    for (int st = 1; st < BNODES; st <<= 1) {
        unsigned v = 0;
        if (t < BNODES) { v = sc[t]; if (t >= st) v += sc[t - st]; }
        __syncthreads();
        if (t < BNODES) sc[t] = v;
        __syncthreads();
    }
    if (t < BNODES) {
        unsigned excl = sc[t] - cnt[t];
        cur[t] = excl;
        int n = b * BNODES + t;
        if (n < N) {
            off[n] = dbase + (int)excl;
            dinv[n] = rsqrtf((float)cnt[t] + 1.0f);
        }
    }
    if (b == 0 && t == 0) off[N] = E;
    __syncthreads();
    for (int c = sg; c < NC; c += 16) {
        int s0 = sS[c], len = sC[c];
        for (int o = sl; o < len; o += 16) {
            unsigned ent = binned[s0 + o];
            unsigned pos = atomicAdd(&cur[ent >> 17], 1u);
            ebkt[dbase + (int)pos] = ent;
        }
    }
}

// ---- wsumk: per src-bucket; LDS-accumulate wsum, write coef2 directly ----
// coef2[n] = {dinv_n, dinv_n * (wsum_n + dinv_n)}
__global__ __launch_bounds__(256) void wsumk_kernel(
    const unsigned* __restrict__ binned2, const int* __restrict__ startsT2,
    const int* __restrict__ countsT2, const float* __restrict__ dinv,
    float2* __restrict__ coef2, int N, int NB, int NC) {
    __shared__ float wsl[BNODES];
    __shared__ int sS[256], sC[256];
    int t = threadIdx.x;
    int b = blockIdx.x;
    if (t < BNODES) wsl[t] = 0.f;
    if (t < NC) { sS[t] = startsT2[(size_t)t * NB + b]; sC[t] = countsT2[(size_t)t * NB + b]; }
    __syncthreads();
    int sg = t >> 4, sl = t & 15;
    for (int c = sg; c < NC; c += 16) {
        int s0 = sS[c], len = sC[c];
        for (int o = sl; o < len; o += 16) {
            unsigned ent = binned2[s0 + o];
            atomicAdd(&wsl[ent >> 17], dinv[ent & 0x1FFFFu]);
        }
    }
    __syncthreads();
    if (t < BNODES) {
        int n = b * BNODES + t;
        if (n < N) {
            float di = dinv[n];
            coef2[n] = make_float2(di, di * (wsl[t] + di));
        }
    }
}

// ---- gemm1 (MFMA): xws4 = fp4(8 * dinv * (x @ W1)) -- fp4 packed in-kernel ----
// Epilogue: wave-private LDS transpose [16 rows][65 floats] (pad -> no 32-way
// read conflicts; same-wave LDS ordering, no barrier), then each lane packs
// 16 contiguous floats into 2 fp4 words, stored as one coalesced uint2.
__global__ __launch_bounds__(256) void gemm1_kernel(
    const float* __restrict__ x, const float* __restrict__ W,
    const float* __restrict__ dinv, unsigned* __restrict__ xws4w, int N) {
    __shared__ float xp[4][16 * 65];
    int t = threadIdx.x;
    int lane = t & 63;
    int wv = t >> 6;
    int n16 = lane & 15;
    int quad = lane >> 4;
    float* xpw = xp[wv];
    bf16x8 bf[4][2];
#pragma unroll
    for (int cg = 0; cg < 4; ++cg)
#pragma unroll
        for (int kh = 0; kh < 2; ++kh)
#pragma unroll
            for (int j = 0; j < 8; ++j)
                bf[cg][kh][j] = (short)f2bf(W[(kh * 32 + quad * 8 + j) * 64 + cg * 16 + n16]);
    int tiles = (N + 15) >> 4;
    int wave = (blockIdx.x * blockDim.x + t) >> 6;
    int nw = (gridDim.x * blockDim.x) >> 6;
    // reader role (fixed per lane): local row lane>>2, words (lane&3)*2, +1
    int lr = lane >> 2;
    int wi = (lane & 3) * 2;
    for (int tile = wave; tile < tiles; tile += nw) {
        int nbase = tile << 4;
        int m = nbase + n16;
        bf16x8 af[2];
        if (m < N) {
            const float* xr = x + (size_t)m * C1;
#pragma unroll
            for (int kh = 0; kh < 2; ++kh) {
                float4 p0 = *(const float4*)(xr + kh * 32 + quad * 8);
                float4 p1 = *(const float4*)(xr + kh * 32 + quad * 8 + 4);
                af[kh][0] = (short)f2bf(p0.x); af[kh][1] = (short)f2bf(p0.y);
                af[kh][2] = (short)f2bf(p0.z); af[kh][3] = (short)f2bf(p0.w);
                af[kh][4] = (short)f2bf(p1.x); af[kh][5] = (short)f2bf(p1.y);
                af[kh][6] = (short)f2bf(p1.z); af[kh][7] = (short)f2bf(p1.w);
            }
        } else {
            af[0] = (bf16x8)(short)0;
            af[1] = (bf16x8)(short)0;
        }
        f32x4 acc[4];
#pragma unroll
        for (int cg = 0; cg < 4; ++cg) {
            acc[cg] = (f32x4)0.f;
            acc[cg] = __builtin_amdgcn_mfma_f32_16x16x32_bf16(af[0], bf[cg][0], acc[cg], 0, 0, 0);
            acc[cg] = __builtin_amdgcn_mfma_f32_16x16x32_bf16(af[1], bf[cg][1], acc[cg], 0, 0, 0);
        }
        int r0 = quad * 4;
#pragma unroll
        for (int reg = 0; reg < 4; ++reg) {
            int row = nbase + r0 + reg;
            float dvr = (row < N) ? dinv[row] : 0.f;
#pragma unroll
            for (int cg = 0; cg < 4; ++cg)
                xpw[(r0 + reg) * 65 + cg * 16 + n16] = dvr * acc[cg][reg];
        }
        // same-wave LDS write->read: ordered by lgkmcnt, no barrier needed
        int grow = nbase + lr;
        if (grow < N) {
            const float* rp = xpw + lr * 65 + wi * 8;
            float f[16];
#pragma unroll
            for (int j = 0; j < 16; ++j) f[j] = rp[j];
            uint2 uu;
            uu.x = fp4x8_encode(f);
            uu.y = fp4x8_encode(f + 8);
            *(uint2*)(xws4w + (size_t)grow * 8 + wi) = uu;
        }
    }
}

// ---- gather1g: quarter-slot per node; fp4 gather + relu + weighted reduce ----
__global__ __launch_bounds__(256) void gather1g_kernel(
    const unsigned short* __restrict__ xws4h, const unsigned* __restrict__ ep,
    const int* __restrict__ off, const float2* __restrict__ coef2,
    const float* __restrict__ b1, float* __restrict__ partial, int N) {
    int t = threadIdx.x;
    int lane = t & 63;
    int c4 = t & 15;
    int n = (blockIdx.x * 256 + t) >> 4;  // slot == node
    float4 bb = ((const float4*)b1)[c4];
    float p0 = 0.f, p1 = 0.f, p2 = 0.f, p3 = 0.f;
    if (n < N) {
        unsigned sw = (unsigned)xws4h[(size_t)n * 16 + c4];
        float2 cf = coef2[n];
        int e0 = off[n], e1 = off[n + 1];
        float a0 = 0.f, a1 = 0.f, a2 = 0.f, a3 = 0.f;
        for (int e = e0; e < e1; e += 16) {
            int m = e1 - e;
            int idx = e + c4;
            unsigned ent = (idx < e1) ? ep[idx] : 0u;
#pragma unroll
            for (int j = 0; j < 16; ++j) {
                unsigned ej = __shfl(ent, (lane & 48) | j);
                if (j < m) {
                    unsigned w = (unsigned)xws4h[(size_t)(ej & 0x1FFFFu) * 16 + c4];
                    float v0, v1, v2, v3;
                    fp4x2_decode(w, 0, v0, v1);
                    fp4x2_decode(w, 1, v2, v3);
                    a0 += v0; a1 += v1; a2 += v2; a3 += v3;
                }
            }
        }
        float di = cf.x, wt = cf.y;
        float s0, s1, s2, s3;
        fp4x2_decode(sw, 0, s0, s1);
        fp4x2_decode(sw, 1, s2, s3);
        float dq = di * 0.125f;  // undo the 8x encode scale once
        p0 = wt * fmaxf(dq * (a0 + s0) + bb.x, 0.f);
        p1 = wt * fmaxf(dq * (a1 + s1) + bb.y, 0.f);
        p2 = wt * fmaxf(dq * (a2 + s2) + bb.z, 0.f);
        p3 = wt * fmaxf(dq * (a3 + s3) + bb.w, 0.f);
    }
    __shared__ float red[256][4];
    red[t][0] = p0; red[t][1] = p1; red[t][2] = p2; red[t][3] = p3;
    __syncthreads();
    if (t < 64) {
        int c4r = t >> 2, q = t & 3;
        float s = 0.f;
#pragma unroll
        for (int k = 0; k < 16; ++k) s += red[c4r + 16 * k][q];
        partial[(size_t)blockIdx.x * 64 + t] = s;
    }
}

// ---- reduceF: column-sum partial -> pooled64; last block does log_softmax ----
__global__ __launch_bounds__(256) void reduceF_kernel(
    const float* __restrict__ partial, float* __restrict__ pooled64, int nrows,
    const float* __restrict__ W2, const float* __restrict__ b2, int N,
    float* __restrict__ out, unsigned* __restrict__ ticket, int nblocks) {
    int t = threadIdx.x;
    int ch = t & 63, rs = t >> 6;
    int r0 = blockIdx.x * 98, r1 = min(nrows, r0 + 98);
    float p = 0.f;
    for (int r = r0 + rs; r < r1; r += 4) p += partial[(size_t)r * 64 + ch];
    __shared__ float red[4][64];
    red[rs][ch] = p;
    __syncthreads();
    if (t < 64) atomicAdd(&pooled64[t], red[0][t] + red[1][t] + red[2][t] + red[3][t]);
    __threadfence();
    __shared__ unsigned last;
    if (t == 0) last = atomicAdd(ticket, 1u);
    __syncthreads();
    if (last == (unsigned)(nblocks - 1)) {
        __shared__ float pl[64];
        if (t < 64) pl[t] = atomicAdd(&pooled64[t], 0.f);  // device-coherent read
        __syncthreads();
        if (t < 32) {
            int c = t;
            float acc = 0.f;
#pragma unroll
            for (int k = 0; k < 64; ++k) acc += pl[k] * W2[k * 32 + c];
            float v = acc / (float)N + b2[c];
            float m = v;
            for (int o = 16; o; o >>= 1) m = fmaxf(m, __shfl_xor(m, o));
            float s = __expf(v - m);
            for (int o = 16; o; o >>= 1) s += __shfl_xor(s, o);
            out[c] = v - m - logf(s);
        }
    }
}

extern "C" void kernel_launch(void* const* d_in, const int* in_sizes, int n_in,
                              void* d_out, int out_size, void* d_ws, size_t ws_size,
                              hipStream_t stream) {
    const float* x  = (const float*)d_in[0];
    const int*   ei = (const int*)d_in[1];
    const float* W1 = (const float*)d_in[2];
    const float* b1 = (const float*)d_in[3];
    const float* W2 = (const float*)d_in[4];
    const float* b2 = (const float*)d_in[5];
    float* out = (float*)d_out;

    int N = in_sizes[0] / C1;
    int E = in_sizes[1] / 2;
    const int* src = ei;
    const int* dst = ei + E;
    int NB = (N + BNODES - 1) / BNODES;   // 782
    int NC = (E + CHUNK - 1) / CHUNK;     // 196 (<= 256)
    int g1blocks = (N + 15) / 16;         // 6250 (slot == node)
    int nwords4 = N * 8;                  // fp4 table words
    int rblocks = (g1blocks + 97) / 98;

    char* ws = (char*)d_ws;
    size_t o = 0;
    auto alloc = [&](size_t bytes) { void* p = ws + o; o = (o + bytes + 255) & ~(size_t)255; return p; };
    unsigned*      btot     = (unsigned*)alloc((size_t)(NB + 1) * 4);
    int*           startsT  = (int*)alloc((size_t)NC * NB * 4);
    int*           countsT  = (int*)alloc((size_t)NC * NB * 4);
    int*           startsT2 = (int*)alloc((size_t)NC * NB * 4);
    int*           countsT2 = (int*)alloc((size_t)NC * NB * 4);
    float*         dinv     = (float*)alloc((size_t)N * 4);
    int*           off      = (int*)alloc((size_t)(N + 1) * 4);
    float2*        coef2    = (float2*)alloc((size_t)N * 8);
    float*         zbuf     = (float*)alloc(68 * 4);  // pooled64[64] + ticket
    unsigned*      binned   = (unsigned*)alloc((size_t)E * 4);
    unsigned*      binned2  = (unsigned*)alloc((size_t)E * 4);
    unsigned*      ebkt     = (unsigned*)alloc((size_t)E * 4);
    unsigned*      xws4     = (unsigned*)alloc((size_t)nwords4 * 4);
    float*         partial  = (float*)alloc((size_t)g1blocks * 64 * 4);
    float*         pooled64 = zbuf;
    unsigned*      ticket   = (unsigned*)(zbuf + 64);

    hipMemsetAsync(btot, 0, (size_t)(NB + 1) * 4, stream);
    hipMemsetAsync(zbuf, 0, 68 * 4, stream);

    binAB_kernel<<<NC * 2, 256, 0, stream>>>(src, dst, E, NB, NC, binned, startsT, countsT,
                                             binned2, startsT2, countsT2, btot);
    compact2_kernel<<<NB, 256, 0, stream>>>(binned, startsT, countsT, btot, N, NB, NC, E,
                                            ebkt, off, dinv);
    wsumk_kernel<<<NB, 256, 0, stream>>>(binned2, startsT2, countsT2, dinv, coef2, N, NB, NC);
    gemm1_kernel<<<256, 256, 0, stream>>>(x, W1, dinv, xws4, N);
    gather1g_kernel<<<g1blocks, 256, 0, stream>>>((const unsigned short*)xws4, ebkt, off,
                                                  coef2, b1, partial, N);
    reduceF_kernel<<<rblocks, 256, 0, stream>>>(partial, pooled64, g1blocks, W2, b2, N,
                                                out, ticket, rblocks);
}